// Round 1
// baseline (1771.972 us; speedup 1.0000x reference)
//
#include <hip/hip_runtime.h>
#include <hip/hip_bf16.h>
#include <math.h>

#define N_TOK 8192
#define HIDD  1024
#define FFND  4096
#define NE    8
#define CAP   2560
#define TMX   20   // CAP/128

typedef __attribute__((ext_vector_type(4))) float  f32x4;
typedef __attribute__((ext_vector_type(8))) __bf16 bf16x8;

__device__ __forceinline__ unsigned short f2bf(float f) {
    unsigned u = __float_as_uint(f);
    u = (u + 0x7fffu + ((u >> 16) & 1u)) >> 16;   // RNE
    return (unsigned short)u;
}

__device__ __forceinline__ void gld_lds16(const void* g, void* l) {
    __builtin_amdgcn_global_load_lds(
        (const __attribute__((address_space(1))) unsigned int*)g,
        (__attribute__((address_space(3))) unsigned int*)l, 16, 0, 0);
}

// ---------------- x fp32 -> bf16 ----------------
__global__ __launch_bounds__(256) void cvt_x_kernel(const float* __restrict__ x,
                                                    unsigned short* __restrict__ xbf) {
    size_t i = (size_t)blockIdx.x * 256 + threadIdx.x;  // float4 index, exactly 2M
    float4 v = reinterpret_cast<const float4*>(x)[i];
    unsigned lo = (unsigned)f2bf(v.x) | ((unsigned)f2bf(v.y) << 16);
    unsigned hi = (unsigned)f2bf(v.z) | ((unsigned)f2bf(v.w) << 16);
    reinterpret_cast<uint2*>(xbf)[i] = make_uint2(lo, hi);
}

// ---------------- router: wave per token ----------------
__global__ __launch_bounds__(256) void router_kernel(const float* __restrict__ x,
                                                     const float* __restrict__ rw,
                                                     int* __restrict__ cnt,
                                                     int* __restrict__ tok,
                                                     float* __restrict__ gate) {
    int lane = threadIdx.x & 63;
    int t = blockIdx.x * 4 + (threadIdx.x >> 6);
    const float4* xr  = reinterpret_cast<const float4*>(x) + (size_t)t * 256;
    const float4* rwr = reinterpret_cast<const float4*>(rw);
    float dot[NE];
#pragma unroll
    for (int e = 0; e < NE; e++) dot[e] = 0.f;
#pragma unroll
    for (int c = 0; c < 4; c++) {
        float4 xv = xr[c * 64 + lane];
#pragma unroll
        for (int e = 0; e < NE; e++) {
            float4 wv = rwr[e * 256 + c * 64 + lane];
            dot[e] += xv.x * wv.x + xv.y * wv.y + xv.z * wv.z + xv.w * wv.w;
        }
    }
#pragma unroll
    for (int e = 0; e < NE; e++) {
        float v = dot[e];
#pragma unroll
        for (int o = 32; o > 0; o >>= 1) v += __shfl_xor(v, o, 64);
        dot[e] = v;
    }
    if (lane == 0) {
        int e0 = 0; float l0 = dot[0];
#pragma unroll
        for (int e = 1; e < NE; e++) if (dot[e] > l0) { l0 = dot[e]; e0 = e; }
        int e1 = -1; float l1 = -3.4e38f;
#pragma unroll
        for (int e = 0; e < NE; e++) if (e != e0 && dot[e] > l1) { l1 = dot[e]; e1 = e; }
        float d  = expf(l1 - l0);
        float g0 = 1.f / (1.f + d);
        float g1 = 1.f - g0;
        int p0 = atomicAdd(&cnt[e0], 1);
        if (p0 < CAP) { tok[e0 * CAP + p0] = t; gate[e0 * CAP + p0] = g0; }
        int p1 = atomicAdd(&cnt[NE + e1], 1);
        if (p1 < CAP) { tok[(NE + e1) * CAP + p1] = t; gate[(NE + e1) * CAP + p1] = g1; }
    }
}

// ---------------- fused-expert GEMM (templated: GEMM1 = x@w1+gelu->h, GEMM2 = h@w2->scatter out) ----
template <int KD, int ND, bool G1>
__global__ __launch_bounds__(256) void ffn_gemm(const unsigned short* __restrict__ A,
                                                const float* __restrict__ W,
                                                unsigned short* __restrict__ H,
                                                float* __restrict__ O,
                                                const int* __restrict__ cntAll,
                                                const int* __restrict__ tokL,
                                                const float* __restrict__ gateL,
                                                int kslot) {
    constexpr int TN = ND / 128;
    int bid = blockIdx.x;
    int tn  = bid % TN;
    int tme = bid / TN;
    int tm  = tme % TMX;
    int e   = tme / TMX;
    const int* cnt = cntAll + kslot * NE;
    int cnt_e = min(cnt[e], CAP);
    if (tm * 128 >= cnt_e) return;
    int off_e = 0;
#pragma unroll
    for (int i = 0; i < NE; i++) off_e += (i < e) ? min(cnt[i], CAP) : 0;
    const int lbase = (kslot * NE + e) * CAP;

    __shared__ __align__(16) unsigned short At[128 * 32];
    __shared__ __align__(16) unsigned short Bt[128 * 32];

    int tid = threadIdx.x;
    int w = tid >> 6, l = tid & 63;
    int wr = w >> 1, wc = w & 1;

    // ---- A staging (global_load_lds, swizzled source chunks) ----
    int r1 = tid >> 2, q1 = tid & 3;
    int r2 = r1 + 64;
    const char* aSrc1;
    const char* aSrc2;
    if (G1) {
        int p1 = tm * 128 + r1, p2 = tm * 128 + r2;
        int t1 = tokL[lbase + (p1 < cnt_e ? p1 : 0)];
        int t2 = tokL[lbase + (p2 < cnt_e ? p2 : 0)];
        aSrc1 = (const char*)(A + (size_t)t1 * KD) + ((q1 ^ ((r1 >> 1) & 3)) << 4);
        aSrc2 = (const char*)(A + (size_t)t2 * KD) + ((q1 ^ ((r2 >> 1) & 3)) << 4);
    } else {
        size_t row1 = (size_t)off_e + tm * 128 + r1;
        size_t row2 = row1 + 64;
        aSrc1 = (const char*)(A + row1 * KD) + ((q1 ^ ((r1 >> 1) & 3)) << 4);
        aSrc2 = (const char*)(A + row2 * KD) + ((q1 ^ ((r2 >> 1) & 3)) << 4);
    }
    char* aDst1 = (char*)At + w * 1024;
    char* aDst2 = aDst1 + 4096;

    // ---- B staging precompute (fp32 -> bf16 transpose into LDS [n][k], swizzled) ----
    const float* bSrc[4];
    int bOff[16];
#pragma unroll
    for (int j = 0; j < 4; j++) {
        int fidx = j * 1024 + tid * 4;
        int kk = fidx >> 7, n = fidx & 127;
        bSrc[j] = W + (size_t)e * KD * ND + (size_t)kk * ND + tn * 128 + n;
#pragma unroll
        for (int i = 0; i < 4; i++) {
            int nn = n + i;
            bOff[j * 4 + i] = nn * 64 + ((((kk >> 3) ^ ((nn >> 1) & 3))) << 4) + ((kk & 7) << 1);
        }
    }

    // ---- fragment read offsets (constant across K) ----
    int aro[4], bro[4];
#pragma unroll
    for (int m = 0; m < 4; m++) {
        int r = wr * 64 + m * 16 + (l & 15);
        aro[m] = r * 64 + (((l >> 4) ^ ((r >> 1) & 3)) << 4);
        int c = wc * 64 + m * 16 + (l & 15);
        bro[m] = c * 64 + (((l >> 4) ^ ((c >> 1) & 3)) << 4);
    }

    f32x4 zf = {0.f, 0.f, 0.f, 0.f};
    f32x4 acc[4][4];
#pragma unroll
    for (int m = 0; m < 4; m++)
#pragma unroll
        for (int n = 0; n < 4; n++) acc[m][n] = zf;

    for (int k0 = 0; k0 < KD; k0 += 32) {
        gld_lds16(aSrc1 + (size_t)k0 * 2, aDst1);
        gld_lds16(aSrc2 + (size_t)k0 * 2, aDst2);
        float4 bv[4];
#pragma unroll
        for (int j = 0; j < 4; j++) bv[j] = *reinterpret_cast<const float4*>(bSrc[j] + (size_t)k0 * ND);
        char* btc = (char*)Bt;
#pragma unroll
        for (int j = 0; j < 4; j++) {
            *(unsigned short*)(btc + bOff[j * 4 + 0]) = f2bf(bv[j].x);
            *(unsigned short*)(btc + bOff[j * 4 + 1]) = f2bf(bv[j].y);
            *(unsigned short*)(btc + bOff[j * 4 + 2]) = f2bf(bv[j].z);
            *(unsigned short*)(btc + bOff[j * 4 + 3]) = f2bf(bv[j].w);
        }
        __syncthreads();
        bf16x8 af[4], bf[4];
#pragma unroll
        for (int m = 0; m < 4; m++) af[m] = *reinterpret_cast<const bf16x8*>((const char*)At + aro[m]);
#pragma unroll
        for (int n = 0; n < 4; n++) bf[n] = *reinterpret_cast<const bf16x8*>((const char*)Bt + bro[n]);
#pragma unroll
        for (int m = 0; m < 4; m++)
#pragma unroll
            for (int n = 0; n < 4; n++)
                acc[m][n] = __builtin_amdgcn_mfma_f32_16x16x32_bf16(af[m], bf[n], acc[m][n], 0, 0, 0);
        __syncthreads();
    }

    if (G1) {
#pragma unroll
        for (int m = 0; m < 4; m++) {
#pragma unroll
            for (int j = 0; j < 4; j++) {
                int rr = wr * 64 + m * 16 + (l >> 4) * 4 + j;
                int p = tm * 128 + rr;
                if (p < cnt_e) {
                    size_t row = (size_t)(off_e + p);
                    unsigned short* hp = H + row * ND + tn * 128 + wc * 64 + (l & 15);
#pragma unroll
                    for (int n = 0; n < 4; n++) {
                        float v = acc[m][n][j];
                        float g = 0.5f * v * (1.f + erff(v * 0.70710678118654752f));
                        hp[n * 16] = f2bf(g);
                    }
                }
            }
        }
    } else {
#pragma unroll
        for (int m = 0; m < 4; m++) {
#pragma unroll
            for (int j = 0; j < 4; j++) {
                int rr = wr * 64 + m * 16 + (l >> 4) * 4 + j;
                int p = tm * 128 + rr;
                if (p < cnt_e) {
                    int t = tokL[lbase + p];
                    float gv = gateL[lbase + p];
                    float* op = O + (size_t)t * ND + tn * 128 + wc * 64 + (l & 15);
#pragma unroll
                    for (int n = 0; n < 4; n++) op[n * 16] += gv * acc[m][n][j];
                }
            }
        }
    }
}

extern "C" void kernel_launch(void* const* d_in, const int* in_sizes, int n_in,
                              void* d_out, int out_size, void* d_ws, size_t ws_size,
                              hipStream_t stream) {
    const float* x  = (const float*)d_in[0];
    const float* rw = (const float*)d_in[1];
    const float* w1 = (const float*)d_in[2];
    const float* w2 = (const float*)d_in[3];
    float* out = (float*)d_out;
    char* ws = (char*)d_ws;

    int*   cnt  = (int*)ws;                                   // 16 ints
    int*   tok  = (int*)(ws + 1024);                          // 2*8*2560 ints
    float* gate = (float*)(ws + 1024 + 2 * NE * CAP * 4);
    unsigned short* xbf = (unsigned short*)(ws + (1 << 20));                     // 16.8 MB
    unsigned short* h   = (unsigned short*)(ws + (1 << 20) + (size_t)N_TOK * HIDD * 2); // 68.2 MB

    hipMemsetAsync(cnt, 0, 64, stream);
    hipMemsetAsync(d_out, 0, (size_t)N_TOK * HIDD * 4, stream);

    hipLaunchKernelGGL(cvt_x_kernel, dim3((N_TOK * HIDD / 4) / 256), dim3(256), 0, stream, x, xbf);
    hipLaunchKernelGGL(router_kernel, dim3(N_TOK / 4), dim3(256), 0, stream, x, rw, cnt, tok, gate);

    for (int k = 0; k < 2; k++) {
        hipLaunchKernelGGL((ffn_gemm<HIDD, FFND, true>), dim3(NE * TMX * (FFND / 128)), dim3(256), 0, stream,
                           xbf, w1, h, (float*)nullptr, cnt, tok, gate, k);
        hipLaunchKernelGGL((ffn_gemm<FFND, HIDD, false>), dim3(NE * TMX * (HIDD / 128)), dim3(256), 0, stream,
                           h, w2, (unsigned short*)nullptr, out, cnt, tok, gate, k);
    }
}

// Round 2
// 820.646 us; speedup vs baseline: 2.1592x; 2.1592x over previous
//
#include <hip/hip_runtime.h>
#include <hip/hip_bf16.h>
#include <math.h>

#define N_TOK 8192
#define HIDD  1024
#define FFND  4096
#define NE    8
#define CAP   2560
#define TMX   20   // CAP/128

typedef __attribute__((ext_vector_type(4))) float  f32x4;
typedef __attribute__((ext_vector_type(8))) __bf16 bf16x8;

__device__ __forceinline__ unsigned short f2bf(float f) {
    unsigned u = __float_as_uint(f);
    u = (u + 0x7fffu + ((u >> 16) & 1u)) >> 16;   // RNE
    return (unsigned short)u;
}

__device__ __forceinline__ void gld_lds16(const void* g, void* l) {
    __builtin_amdgcn_global_load_lds(
        (const __attribute__((address_space(1))) unsigned int*)g,
        (__attribute__((address_space(3))) unsigned int*)l, 16, 0, 0);
}

// ---------------- x fp32 -> bf16 ----------------
__global__ __launch_bounds__(256) void cvt_x_kernel(const float* __restrict__ x,
                                                    unsigned short* __restrict__ xbf) {
    size_t i = (size_t)blockIdx.x * 256 + threadIdx.x;
    float4 v = reinterpret_cast<const float4*>(x)[i];
    unsigned lo = (unsigned)f2bf(v.x) | ((unsigned)f2bf(v.y) << 16);
    unsigned hi = (unsigned)f2bf(v.z) | ((unsigned)f2bf(v.w) << 16);
    reinterpret_cast<uint2*>(xbf)[i] = make_uint2(lo, hi);
}

// ---------------- weight fp32 [e][R][C] -> bf16 transposed [e][C][R] ----------------
template <int R, int C>
__global__ __launch_bounds__(256) void transpose_cvt(const float* __restrict__ W,
                                                     unsigned short* __restrict__ Wt) {
    __shared__ unsigned short st[64][72];   // 16B-aligned rows (144B stride)
    int e  = blockIdx.z;
    int r0 = blockIdx.y * 64, c0 = blockIdx.x * 64;
    int tid = threadIdx.x;
    int rb = tid >> 4, cq = tid & 15;
    const float* src = W + ((size_t)e * R + r0) * C + c0;
#pragma unroll
    for (int i = 0; i < 4; i++) {
        int kr = i * 16 + rb;
        float4 v = *reinterpret_cast<const float4*>(src + (size_t)kr * C + cq * 4);
        st[cq * 4 + 0][kr] = f2bf(v.x);
        st[cq * 4 + 1][kr] = f2bf(v.y);
        st[cq * 4 + 2][kr] = f2bf(v.z);
        st[cq * 4 + 3][kr] = f2bf(v.w);
    }
    __syncthreads();
    unsigned short* dst = Wt + ((size_t)e * C + c0) * R + r0;
#pragma unroll
    for (int i = 0; i < 4; i++) {
        int cr = i * 16 + rb;
        uint2 v = *reinterpret_cast<const uint2*>(&st[cr][cq * 4]);
        *reinterpret_cast<uint2*>(dst + (size_t)cr * R + cq * 4) = v;
    }
}

// ---------------- router: wave per token ----------------
__global__ __launch_bounds__(256) void router_kernel(const float* __restrict__ x,
                                                     const float* __restrict__ rw,
                                                     int* __restrict__ cnt,
                                                     int* __restrict__ tok,
                                                     float* __restrict__ gate) {
    int lane = threadIdx.x & 63;
    int t = blockIdx.x * 4 + (threadIdx.x >> 6);
    const float4* xr  = reinterpret_cast<const float4*>(x) + (size_t)t * 256;
    const float4* rwr = reinterpret_cast<const float4*>(rw);
    float dot[NE];
#pragma unroll
    for (int e = 0; e < NE; e++) dot[e] = 0.f;
#pragma unroll
    for (int c = 0; c < 4; c++) {
        float4 xv = xr[c * 64 + lane];
#pragma unroll
        for (int e = 0; e < NE; e++) {
            float4 wv = rwr[e * 256 + c * 64 + lane];
            dot[e] += xv.x * wv.x + xv.y * wv.y + xv.z * wv.z + xv.w * wv.w;
        }
    }
#pragma unroll
    for (int e = 0; e < NE; e++) {
        float v = dot[e];
#pragma unroll
        for (int o = 32; o > 0; o >>= 1) v += __shfl_xor(v, o, 64);
        dot[e] = v;
    }
    if (lane == 0) {
        int e0 = 0; float l0 = dot[0];
#pragma unroll
        for (int e = 1; e < NE; e++) if (dot[e] > l0) { l0 = dot[e]; e0 = e; }
        int e1 = -1; float l1 = -3.4e38f;
#pragma unroll
        for (int e = 0; e < NE; e++) if (e != e0 && dot[e] > l1) { l1 = dot[e]; e1 = e; }
        float d  = expf(l1 - l0);
        float g0 = 1.f / (1.f + d);
        float g1 = 1.f - g0;
        int p0 = atomicAdd(&cnt[e0], 1);
        if (p0 < CAP) { tok[e0 * CAP + p0] = t; gate[e0 * CAP + p0] = g0; }
        int p1 = atomicAdd(&cnt[NE + e1], 1);
        if (p1 < CAP) { tok[(NE + e1) * CAP + p1] = t; gate[(NE + e1) * CAP + p1] = g1; }
    }
}

// ======== FAST path: both operands bf16 row-major-in-k, staged via global_load_lds ========
template <int KD, int ND, bool G1>
__global__ __launch_bounds__(256) void ffn_gemm_f(const unsigned short* __restrict__ A,
                                                  const unsigned short* __restrict__ Bw, // [e][n][k] bf16
                                                  unsigned short* __restrict__ H,
                                                  float* __restrict__ O,
                                                  const int* __restrict__ cntAll,
                                                  const int* __restrict__ tokL,
                                                  const float* __restrict__ gateL,
                                                  int kslot) {
    constexpr int TN = ND / 128;
    int bid = blockIdx.x;
    int tn  = bid % TN;
    int tme = bid / TN;
    int tm  = tme % TMX;
    int e   = tme / TMX;
    const int* cnt = cntAll + kslot * NE;
    int cnt_e = min(cnt[e], CAP);
    if (tm * 128 >= cnt_e) return;
    int off_e = 0;
#pragma unroll
    for (int i = 0; i < NE; i++) off_e += (i < e) ? min(cnt[i], CAP) : 0;
    const int lbase = (kslot * NE + e) * CAP;

    __shared__ __align__(16) unsigned short At[128 * 32];
    __shared__ __align__(16) unsigned short Bt[128 * 32];

    int tid = threadIdx.x;
    int w = tid >> 6, l = tid & 63;
    int wr = w >> 1, wc = w & 1;

    // staging geometry: r = tid>>2 covers rows 0..63 (call 1) / 64..127 (call 2),
    // q = tid&3 is the 16B chunk; source chunk pre-swizzled by XOR((r>>1)&3)
    int r1 = tid >> 2, q1 = tid & 3;
    int r2 = r1 + 64;

    const char* aSrc1;
    const char* aSrc2;
    if (G1) {
        int p1 = tm * 128 + r1, p2 = tm * 128 + r2;
        int t1 = tokL[lbase + (p1 < cnt_e ? p1 : 0)];
        int t2 = tokL[lbase + (p2 < cnt_e ? p2 : 0)];
        aSrc1 = (const char*)(A + (size_t)t1 * KD) + ((q1 ^ ((r1 >> 1) & 3)) << 4);
        aSrc2 = (const char*)(A + (size_t)t2 * KD) + ((q1 ^ ((r2 >> 1) & 3)) << 4);
    } else {
        size_t row1 = (size_t)off_e + tm * 128 + r1;
        size_t row2 = row1 + 64;
        aSrc1 = (const char*)(A + row1 * KD) + ((q1 ^ ((r1 >> 1) & 3)) << 4);
        aSrc2 = (const char*)(A + row2 * KD) + ((q1 ^ ((r2 >> 1) & 3)) << 4);
    }
    const char* bSrc1 = (const char*)(Bw + ((size_t)e * ND + tn * 128 + r1) * KD) + ((q1 ^ ((r1 >> 1) & 3)) << 4);
    const char* bSrc2 = (const char*)(Bw + ((size_t)e * ND + tn * 128 + r2) * KD) + ((q1 ^ ((r2 >> 1) & 3)) << 4);

    char* aDst1 = (char*)At + w * 1024;
    char* aDst2 = aDst1 + 4096;
    char* bDst1 = (char*)Bt + w * 1024;
    char* bDst2 = bDst1 + 4096;

    int aro[4], bro[4];
#pragma unroll
    for (int m = 0; m < 4; m++) {
        int r = wr * 64 + m * 16 + (l & 15);
        aro[m] = r * 64 + (((l >> 4) ^ ((r >> 1) & 3)) << 4);
        int c = wc * 64 + m * 16 + (l & 15);
        bro[m] = c * 64 + (((l >> 4) ^ ((c >> 1) & 3)) << 4);
    }

    f32x4 zf = {0.f, 0.f, 0.f, 0.f};
    f32x4 acc[4][4];
#pragma unroll
    for (int m = 0; m < 4; m++)
#pragma unroll
        for (int n = 0; n < 4; n++) acc[m][n] = zf;

    for (int k0 = 0; k0 < KD; k0 += 32) {
        size_t kb = (size_t)k0 * 2;
        gld_lds16(aSrc1 + kb, aDst1);
        gld_lds16(aSrc2 + kb, aDst2);
        gld_lds16(bSrc1 + kb, bDst1);
        gld_lds16(bSrc2 + kb, bDst2);
        __syncthreads();
        bf16x8 af[4], bf[4];
#pragma unroll
        for (int m = 0; m < 4; m++) af[m] = *reinterpret_cast<const bf16x8*>((const char*)At + aro[m]);
#pragma unroll
        for (int n = 0; n < 4; n++) bf[n] = *reinterpret_cast<const bf16x8*>((const char*)Bt + bro[n]);
#pragma unroll
        for (int m = 0; m < 4; m++)
#pragma unroll
            for (int n = 0; n < 4; n++)
                acc[m][n] = __builtin_amdgcn_mfma_f32_16x16x32_bf16(af[m], bf[n], acc[m][n], 0, 0, 0);
        __syncthreads();
    }

    if (G1) {
#pragma unroll
        for (int m = 0; m < 4; m++) {
#pragma unroll
            for (int j = 0; j < 4; j++) {
                int rr = wr * 64 + m * 16 + (l >> 4) * 4 + j;
                int p = tm * 128 + rr;
                if (p < cnt_e) {
                    size_t row = (size_t)(off_e + p);
                    unsigned short* hp = H + row * ND + tn * 128 + wc * 64 + (l & 15);
#pragma unroll
                    for (int n = 0; n < 4; n++) {
                        float v = acc[m][n][j];
                        float g = 0.5f * v * (1.f + erff(v * 0.70710678118654752f));
                        hp[n * 16] = f2bf(g);
                    }
                }
            }
        }
    } else {
#pragma unroll
        for (int m = 0; m < 4; m++) {
#pragma unroll
            for (int j = 0; j < 4; j++) {
                int rr = wr * 64 + m * 16 + (l >> 4) * 4 + j;
                int p = tm * 128 + rr;
                if (p < cnt_e) {
                    int t = tokL[lbase + p];
                    float gv = gateL[lbase + p];
                    float* op = O + (size_t)t * ND + tn * 128 + wc * 64 + (l & 15);
#pragma unroll
                    for (int n = 0; n < 4; n++) op[n * 16] += gv * acc[m][n][j];
                }
            }
        }
    }
}

// ======== FALLBACK path (round-1 kernel, used only if ws is too small) ========
template <int KD, int ND, bool G1>
__global__ __launch_bounds__(256) void ffn_gemm(const unsigned short* __restrict__ A,
                                                const float* __restrict__ W,
                                                unsigned short* __restrict__ H,
                                                float* __restrict__ O,
                                                const int* __restrict__ cntAll,
                                                const int* __restrict__ tokL,
                                                const float* __restrict__ gateL,
                                                int kslot) {
    constexpr int TN = ND / 128;
    int bid = blockIdx.x;
    int tn  = bid % TN;
    int tme = bid / TN;
    int tm  = tme % TMX;
    int e   = tme / TMX;
    const int* cnt = cntAll + kslot * NE;
    int cnt_e = min(cnt[e], CAP);
    if (tm * 128 >= cnt_e) return;
    int off_e = 0;
#pragma unroll
    for (int i = 0; i < NE; i++) off_e += (i < e) ? min(cnt[i], CAP) : 0;
    const int lbase = (kslot * NE + e) * CAP;

    __shared__ __align__(16) unsigned short At[128 * 32];
    __shared__ __align__(16) unsigned short Bt[128 * 32];

    int tid = threadIdx.x;
    int w = tid >> 6, l = tid & 63;
    int wr = w >> 1, wc = w & 1;

    int r1 = tid >> 2, q1 = tid & 3;
    int r2 = r1 + 64;
    const char* aSrc1;
    const char* aSrc2;
    if (G1) {
        int p1 = tm * 128 + r1, p2 = tm * 128 + r2;
        int t1 = tokL[lbase + (p1 < cnt_e ? p1 : 0)];
        int t2 = tokL[lbase + (p2 < cnt_e ? p2 : 0)];
        aSrc1 = (const char*)(A + (size_t)t1 * KD) + ((q1 ^ ((r1 >> 1) & 3)) << 4);
        aSrc2 = (const char*)(A + (size_t)t2 * KD) + ((q1 ^ ((r2 >> 1) & 3)) << 4);
    } else {
        size_t row1 = (size_t)off_e + tm * 128 + r1;
        size_t row2 = row1 + 64;
        aSrc1 = (const char*)(A + row1 * KD) + ((q1 ^ ((r1 >> 1) & 3)) << 4);
        aSrc2 = (const char*)(A + row2 * KD) + ((q1 ^ ((r2 >> 1) & 3)) << 4);
    }
    char* aDst1 = (char*)At + w * 1024;
    char* aDst2 = aDst1 + 4096;

    const float* bSrc[4];
    int bOff[16];
#pragma unroll
    for (int j = 0; j < 4; j++) {
        int fidx = j * 1024 + tid * 4;
        int kk = fidx >> 7, n = fidx & 127;
        bSrc[j] = W + (size_t)e * KD * ND + (size_t)kk * ND + tn * 128 + n;
#pragma unroll
        for (int i = 0; i < 4; i++) {
            int nn = n + i;
            bOff[j * 4 + i] = nn * 64 + ((((kk >> 3) ^ ((nn >> 1) & 3))) << 4) + ((kk & 7) << 1);
        }
    }

    int aro[4], bro[4];
#pragma unroll
    for (int m = 0; m < 4; m++) {
        int r = wr * 64 + m * 16 + (l & 15);
        aro[m] = r * 64 + (((l >> 4) ^ ((r >> 1) & 3)) << 4);
        int c = wc * 64 + m * 16 + (l & 15);
        bro[m] = c * 64 + (((l >> 4) ^ ((c >> 1) & 3)) << 4);
    }

    f32x4 zf = {0.f, 0.f, 0.f, 0.f};
    f32x4 acc[4][4];
#pragma unroll
    for (int m = 0; m < 4; m++)
#pragma unroll
        for (int n = 0; n < 4; n++) acc[m][n] = zf;

    for (int k0 = 0; k0 < KD; k0 += 32) {
        gld_lds16(aSrc1 + (size_t)k0 * 2, aDst1);
        gld_lds16(aSrc2 + (size_t)k0 * 2, aDst2);
        float4 bv[4];
#pragma unroll
        for (int j = 0; j < 4; j++) bv[j] = *reinterpret_cast<const float4*>(bSrc[j] + (size_t)k0 * ND);
        char* btc = (char*)Bt;
#pragma unroll
        for (int j = 0; j < 4; j++) {
            *(unsigned short*)(btc + bOff[j * 4 + 0]) = f2bf(bv[j].x);
            *(unsigned short*)(btc + bOff[j * 4 + 1]) = f2bf(bv[j].y);
            *(unsigned short*)(btc + bOff[j * 4 + 2]) = f2bf(bv[j].z);
            *(unsigned short*)(btc + bOff[j * 4 + 3]) = f2bf(bv[j].w);
        }
        __syncthreads();
        bf16x8 af[4], bf[4];
#pragma unroll
        for (int m = 0; m < 4; m++) af[m] = *reinterpret_cast<const bf16x8*>((const char*)At + aro[m]);
#pragma unroll
        for (int n = 0; n < 4; n++) bf[n] = *reinterpret_cast<const bf16x8*>((const char*)Bt + bro[n]);
#pragma unroll
        for (int m = 0; m < 4; m++)
#pragma unroll
            for (int n = 0; n < 4; n++)
                acc[m][n] = __builtin_amdgcn_mfma_f32_16x16x32_bf16(af[m], bf[n], acc[m][n], 0, 0, 0);
        __syncthreads();
    }

    if (G1) {
#pragma unroll
        for (int m = 0; m < 4; m++) {
#pragma unroll
            for (int j = 0; j < 4; j++) {
                int rr = wr * 64 + m * 16 + (l >> 4) * 4 + j;
                int p = tm * 128 + rr;
                if (p < cnt_e) {
                    size_t row = (size_t)(off_e + p);
                    unsigned short* hp = H + row * ND + tn * 128 + wc * 64 + (l & 15);
#pragma unroll
                    for (int n = 0; n < 4; n++) {
                        float v = acc[m][n][j];
                        float g = 0.5f * v * (1.f + erff(v * 0.70710678118654752f));
                        hp[n * 16] = f2bf(g);
                    }
                }
            }
        }
    } else {
#pragma unroll
        for (int m = 0; m < 4; m++) {
#pragma unroll
            for (int j = 0; j < 4; j++) {
                int rr = wr * 64 + m * 16 + (l >> 4) * 4 + j;
                int p = tm * 128 + rr;
                if (p < cnt_e) {
                    int t = tokL[lbase + p];
                    float gv = gateL[lbase + p];
                    float* op = O + (size_t)t * ND + tn * 128 + wc * 64 + (l & 15);
#pragma unroll
                    for (int n = 0; n < 4; n++) op[n * 16] += gv * acc[m][n][j];
                }
            }
        }
    }
}

extern "C" void kernel_launch(void* const* d_in, const int* in_sizes, int n_in,
                              void* d_out, int out_size, void* d_ws, size_t ws_size,
                              hipStream_t stream) {
    const float* x  = (const float*)d_in[0];
    const float* rw = (const float*)d_in[1];
    const float* w1 = (const float*)d_in[2];
    const float* w2 = (const float*)d_in[3];
    float* out = (float*)d_out;
    char* ws = (char*)d_ws;

    int*   cnt  = (int*)ws;                                   // 16 ints
    int*   tok  = (int*)(ws + 1024);                          // 2*8*2560 ints
    float* gate = (float*)(ws + 1024 + 2 * NE * CAP * 4);
    unsigned short* xbf = (unsigned short*)(ws + (1 << 20));                       // 16.78 MB
    size_t hOff  = (1 << 20) + (size_t)N_TOK * HIDD * 2;
    unsigned short* h = (unsigned short*)(ws + hOff);                              // 8320 rows x 4096 bf16 = 68.2 MB
    size_t w1tOff = hOff + (size_t)(N_TOK + 128) * FFND * 2;
    unsigned short* w1t = (unsigned short*)(ws + w1tOff);                          // 67.1 MB
    size_t w2tOff = w1tOff + (size_t)NE * HIDD * FFND * 2;
    unsigned short* w2t = (unsigned short*)(ws + w2tOff);                          // 67.1 MB
    size_t needed = w2tOff + (size_t)NE * HIDD * FFND * 2;

    hipMemsetAsync(cnt, 0, 64, stream);
    hipMemsetAsync(d_out, 0, (size_t)N_TOK * HIDD * 4, stream);

    hipLaunchKernelGGL(cvt_x_kernel, dim3((N_TOK * HIDD / 4) / 256), dim3(256), 0, stream, x, xbf);
    hipLaunchKernelGGL(router_kernel, dim3(N_TOK / 4), dim3(256), 0, stream, x, rw, cnt, tok, gate);

    if (ws_size >= needed) {
        // bf16-transposed weights: w1t [e][f][h], w2t [e][h][f]
        hipLaunchKernelGGL((transpose_cvt<HIDD, FFND>), dim3(FFND / 64, HIDD / 64, NE), dim3(256), 0, stream, w1, w1t);
        hipLaunchKernelGGL((transpose_cvt<FFND, HIDD>), dim3(HIDD / 64, FFND / 64, NE), dim3(256), 0, stream, w2, w2t);
        for (int k = 0; k < 2; k++) {
            hipLaunchKernelGGL((ffn_gemm_f<HIDD, FFND, true>), dim3(NE * TMX * (FFND / 128)), dim3(256), 0, stream,
                               xbf, w1t, h, (float*)nullptr, cnt, tok, gate, k);
            hipLaunchKernelGGL((ffn_gemm_f<FFND, HIDD, false>), dim3(NE * TMX * (HIDD / 128)), dim3(256), 0, stream,
                               h, w2t, (unsigned short*)nullptr, out, cnt, tok, gate, k);
        }
    } else {
        for (int k = 0; k < 2; k++) {
            hipLaunchKernelGGL((ffn_gemm<HIDD, FFND, true>), dim3(NE * TMX * (FFND / 128)), dim3(256), 0, stream,
                               xbf, w1, h, (float*)nullptr, cnt, tok, gate, k);
            hipLaunchKernelGGL((ffn_gemm<FFND, HIDD, false>), dim3(NE * TMX * (HIDD / 128)), dim3(256), 0, stream,
                               h, w2, (unsigned short*)nullptr, out, cnt, tok, gate, k);
        }
    }
}

// Round 3
// 592.150 us; speedup vs baseline: 2.9924x; 1.3859x over previous
//
#include <hip/hip_runtime.h>
#include <hip/hip_bf16.h>
#include <math.h>

#define N_TOK 8192
#define HIDD  1024
#define FFND  4096
#define NE    8
#define CAP   2560
#define TMX   20   // CAP/128
#define RMAX  16512

typedef __attribute__((ext_vector_type(4))) float  f32x4;
typedef __attribute__((ext_vector_type(8))) __bf16 bf16x8;

__device__ __forceinline__ unsigned short f2bf(float f) {
    unsigned u = __float_as_uint(f);
    u = (u + 0x7fffu + ((u >> 16) & 1u)) >> 16;   // RNE
    return (unsigned short)u;
}

__device__ __forceinline__ void gld_lds16(const void* g, void* l) {
    __builtin_amdgcn_global_load_lds(
        (const __attribute__((address_space(1))) unsigned int*)g,
        (__attribute__((address_space(3))) unsigned int*)l, 16, 0, 0);
}

// ---------------- weight fp32 [e][R][C] -> bf16 transposed [e][C][R] ----------------
template <int R, int C>
__global__ __launch_bounds__(256) void transpose_cvt(const float* __restrict__ W,
                                                     unsigned short* __restrict__ Wt) {
    __shared__ unsigned short st[64][72];
    int e  = blockIdx.z;
    int r0 = blockIdx.y * 64, c0 = blockIdx.x * 64;
    int tid = threadIdx.x;
    int rb = tid >> 4, cq = tid & 15;
    const float* src = W + ((size_t)e * R + r0) * C + c0;
#pragma unroll
    for (int i = 0; i < 4; i++) {
        int kr = i * 16 + rb;
        float4 v = *reinterpret_cast<const float4*>(src + (size_t)kr * C + cq * 4);
        st[cq * 4 + 0][kr] = f2bf(v.x);
        st[cq * 4 + 1][kr] = f2bf(v.y);
        st[cq * 4 + 2][kr] = f2bf(v.z);
        st[cq * 4 + 3][kr] = f2bf(v.w);
    }
    __syncthreads();
    unsigned short* dst = Wt + ((size_t)e * C + c0) * R + r0;
#pragma unroll
    for (int i = 0; i < 4; i++) {
        int cr = i * 16 + rb;
        uint2 v = *reinterpret_cast<const uint2*>(&st[cr][cq * 4]);
        *reinterpret_cast<uint2*>(dst + (size_t)cr * R + cq * 4) = v;
    }
}

// ---------------- fused router + x->bf16: 32 tokens/block, block-aggregated counts ----
__global__ __launch_bounds__(256) void router_kernel(const float* __restrict__ x,
                                                     const float* __restrict__ rw,
                                                     unsigned short* __restrict__ xbf,
                                                     int* __restrict__ cnt,
                                                     int* __restrict__ tok,
                                                     float* __restrict__ gate) {
    __shared__ float4 rwl[2048];          // 32 KB: rw as float4
    __shared__ int   e0s[32], e1s[32];
    __shared__ float g0s[32], g1s[32];
    __shared__ int   baseS[16];

    int tid = threadIdx.x, lane = tid & 63, w = tid >> 6;
    for (int i = tid; i < 2048; i += 256) rwl[i] = reinterpret_cast<const float4*>(rw)[i];
    __syncthreads();

    int tbase = blockIdx.x * 32 + w * 8;
    for (int i = 0; i < 8; i++) {
        int t = tbase + i;
        const float4* xr = reinterpret_cast<const float4*>(x) + (size_t)t * 256;
        float4 xv[4];
#pragma unroll
        for (int c = 0; c < 4; c++) xv[c] = xr[c * 64 + lane];
        uint2* xb = reinterpret_cast<uint2*>(xbf) + (size_t)t * 256;
#pragma unroll
        for (int c = 0; c < 4; c++) {
            uint2 p;
            p.x = (unsigned)f2bf(xv[c].x) | ((unsigned)f2bf(xv[c].y) << 16);
            p.y = (unsigned)f2bf(xv[c].z) | ((unsigned)f2bf(xv[c].w) << 16);
            xb[c * 64 + lane] = p;
        }
        float dot[NE];
#pragma unroll
        for (int e = 0; e < NE; e++) {
            float s = 0.f;
#pragma unroll
            for (int c = 0; c < 4; c++) {
                float4 a = rwl[e * 256 + c * 64 + lane];
                s += xv[c].x * a.x + xv[c].y * a.y + xv[c].z * a.z + xv[c].w * a.w;
            }
            dot[e] = s;
        }
#pragma unroll
        for (int e = 0; e < NE; e++) {
            float v = dot[e];
#pragma unroll
            for (int o = 32; o > 0; o >>= 1) v += __shfl_xor(v, o, 64);
            dot[e] = v;
        }
        if (lane == 0) {
            int e0 = 0; float l0 = dot[0];
#pragma unroll
            for (int e = 1; e < NE; e++) if (dot[e] > l0) { l0 = dot[e]; e0 = e; }
            int e1 = -1; float l1 = -3.4e38f;
#pragma unroll
            for (int e = 0; e < NE; e++) if (e != e0 && dot[e] > l1) { l1 = dot[e]; e1 = e; }
            float g0 = 1.f / (1.f + expf(l1 - l0));
            int j = w * 8 + i;
            e0s[j] = e0; e1s[j] = e1; g0s[j] = g0; g1s[j] = 1.f - g0;
        }
    }
    __syncthreads();

    int e0 = 255, e1 = 255, rank0 = 0, rank1 = 0, slotcnt = 0;
    float g0 = 0.f, g1 = 0.f;
    if (w == 0) {
        if (lane < 32) { e0 = e0s[lane]; e1 = e1s[lane]; g0 = g0s[lane]; g1 = g1s[lane]; }
        unsigned long long lt = (1ull << lane) - 1ull;
#pragma unroll
        for (int ee = 0; ee < NE; ee++) {
            unsigned long long m0 = __ballot(e0 == ee);
            unsigned long long m1 = __ballot(e1 == ee);
            if (e0 == ee) rank0 = (int)__popcll(m0 & lt);
            if (e1 == ee) rank1 = (int)__popcll(m1 & lt);
            if (lane == ee)      slotcnt = (int)__popcll(m0);
            if (lane == NE + ee) slotcnt = (int)__popcll(m1);
        }
        if (lane < 16) baseS[lane] = atomicAdd(&cnt[lane * 16], slotcnt);
    }
    __syncthreads();
    if (w == 0 && lane < 32) {
        int t = blockIdx.x * 32 + lane;
        int p0 = baseS[e0] + rank0;
        if (p0 < CAP) { tok[e0 * CAP + p0] = t; gate[e0 * CAP + p0] = g0; }
        int p1 = baseS[NE + e1] + rank1;
        if (p1 < CAP) { tok[(NE + e1) * CAP + p1] = t; gate[(NE + e1) * CAP + p1] = g1; }
    }
}

// ======== FAST GEMM: A,B bf16 k-contig, staged via global_load_lds; 16 virtual slots ========
template <int KD, int ND, bool G1>
__global__ __launch_bounds__(256) void ffn_gemm_f(const unsigned short* __restrict__ A,
                                                  const unsigned short* __restrict__ Bw, // [e][n][k]
                                                  unsigned short* __restrict__ H,
                                                  float* __restrict__ O,
                                                  const int* __restrict__ cntAll,
                                                  const int* __restrict__ tokL,
                                                  const float* __restrict__ gateL,
                                                  int slot0, int pbase) {
    constexpr int TN = ND / 128;
    int bid = blockIdx.x;
    int tn  = bid % TN;
    int tme = bid / TN;
    int tm  = tme % TMX;
    int s   = slot0 + tme / TMX;      // global slot (k*8+e)
    int eW  = s & 7;                  // weight expert
    int cnt_e = min(cntAll[s * 16], CAP);
    if (tm * 128 >= cnt_e) return;
    int off_e = 0;
#pragma unroll
    for (int i = 0; i < 16; i++) {
        int c = min(cntAll[i * 16], CAP);
        off_e += (i >= pbase && i < s) ? c : 0;
    }
    const int lbase = s * CAP;

    __shared__ __align__(16) unsigned short At[128 * 32];
    __shared__ __align__(16) unsigned short Bt[128 * 32];

    int tid = threadIdx.x;
    int w = tid >> 6, l = tid & 63;
    int wr = w >> 1, wc = w & 1;

    int r1 = tid >> 2, q1 = tid & 3;
    int r2 = r1 + 64;

    const char* aSrc1;
    const char* aSrc2;
    if (G1) {
        int p1 = tm * 128 + r1, p2 = tm * 128 + r2;
        int t1 = tokL[lbase + (p1 < cnt_e ? p1 : 0)];
        int t2 = tokL[lbase + (p2 < cnt_e ? p2 : 0)];
        aSrc1 = (const char*)(A + (size_t)t1 * KD) + ((q1 ^ ((r1 >> 1) & 3)) << 4);
        aSrc2 = (const char*)(A + (size_t)t2 * KD) + ((q1 ^ ((r2 >> 1) & 3)) << 4);
    } else {
        size_t row1 = (size_t)off_e + tm * 128 + r1;
        size_t row2 = row1 + 64;
        aSrc1 = (const char*)(A + row1 * KD) + ((q1 ^ ((r1 >> 1) & 3)) << 4);
        aSrc2 = (const char*)(A + row2 * KD) + ((q1 ^ ((r2 >> 1) & 3)) << 4);
    }
    const char* bSrc1 = (const char*)(Bw + ((size_t)eW * ND + tn * 128 + r1) * KD) + ((q1 ^ ((r1 >> 1) & 3)) << 4);
    const char* bSrc2 = (const char*)(Bw + ((size_t)eW * ND + tn * 128 + r2) * KD) + ((q1 ^ ((r2 >> 1) & 3)) << 4);

    char* aDst1 = (char*)At + w * 1024;
    char* aDst2 = aDst1 + 4096;
    char* bDst1 = (char*)Bt + w * 1024;
    char* bDst2 = bDst1 + 4096;

    int aro[4], bro[4];
#pragma unroll
    for (int m = 0; m < 4; m++) {
        int r = wr * 64 + m * 16 + (l & 15);
        aro[m] = r * 64 + (((l >> 4) ^ ((r >> 1) & 3)) << 4);
        int c = wc * 64 + m * 16 + (l & 15);
        bro[m] = c * 64 + (((l >> 4) ^ ((c >> 1) & 3)) << 4);
    }

    f32x4 zf = {0.f, 0.f, 0.f, 0.f};
    f32x4 acc[4][4];
#pragma unroll
    for (int m = 0; m < 4; m++)
#pragma unroll
        for (int n = 0; n < 4; n++) acc[m][n] = zf;

    for (int k0 = 0; k0 < KD; k0 += 32) {
        size_t kb = (size_t)k0 * 2;
        gld_lds16(aSrc1 + kb, aDst1);
        gld_lds16(aSrc2 + kb, aDst2);
        gld_lds16(bSrc1 + kb, bDst1);
        gld_lds16(bSrc2 + kb, bDst2);
        __syncthreads();
        bf16x8 af[4], bf[4];
#pragma unroll
        for (int m = 0; m < 4; m++) af[m] = *reinterpret_cast<const bf16x8*>((const char*)At + aro[m]);
#pragma unroll
        for (int n = 0; n < 4; n++) bf[n] = *reinterpret_cast<const bf16x8*>((const char*)Bt + bro[n]);
#pragma unroll
        for (int m = 0; m < 4; m++)
#pragma unroll
            for (int n = 0; n < 4; n++)
                acc[m][n] = __builtin_amdgcn_mfma_f32_16x16x32_bf16(af[m], bf[n], acc[m][n], 0, 0, 0);
        __syncthreads();
    }

    if (G1) {
#pragma unroll
        for (int m = 0; m < 4; m++) {
#pragma unroll
            for (int j = 0; j < 4; j++) {
                int rr = wr * 64 + m * 16 + (l >> 4) * 4 + j;
                int p = tm * 128 + rr;
                if (p < cnt_e) {
                    size_t row = (size_t)(off_e + p);
                    unsigned short* hp = H + row * ND + tn * 128 + wc * 64 + (l & 15);
#pragma unroll
                    for (int n = 0; n < 4; n++) {
                        float v = acc[m][n][j];
                        float g = 0.5f * v * (1.f + erff(v * 0.70710678118654752f));
                        hp[n * 16] = f2bf(g);
                    }
                }
            }
        }
    } else {
#pragma unroll
        for (int m = 0; m < 4; m++) {
#pragma unroll
            for (int j = 0; j < 4; j++) {
                int rr = wr * 64 + m * 16 + (l >> 4) * 4 + j;
                int p = tm * 128 + rr;
                if (p < cnt_e) {
                    int t = tokL[lbase + p];
                    float gv = gateL[lbase + p];
                    float* op = O + (size_t)t * ND + tn * 128 + wc * 64 + (l & 15);
#pragma unroll
                    for (int n = 0; n < 4; n++) atomicAdd(op + n * 16, gv * acc[m][n][j]);
                }
            }
        }
    }
}

// ======== FALLBACK path (fp32 weights on the fly; used only if ws is small) ========
template <int KD, int ND, bool G1>
__global__ __launch_bounds__(256) void ffn_gemm(const unsigned short* __restrict__ A,
                                                const float* __restrict__ W,
                                                unsigned short* __restrict__ H,
                                                float* __restrict__ O,
                                                const int* __restrict__ cntAll,
                                                const int* __restrict__ tokL,
                                                const float* __restrict__ gateL,
                                                int slot0, int pbase) {
    constexpr int TN = ND / 128;
    int bid = blockIdx.x;
    int tn  = bid % TN;
    int tme = bid / TN;
    int tm  = tme % TMX;
    int s   = slot0 + tme / TMX;
    int eW  = s & 7;
    int cnt_e = min(cntAll[s * 16], CAP);
    if (tm * 128 >= cnt_e) return;
    int off_e = 0;
#pragma unroll
    for (int i = 0; i < 16; i++) {
        int c = min(cntAll[i * 16], CAP);
        off_e += (i >= pbase && i < s) ? c : 0;
    }
    const int lbase = s * CAP;

    __shared__ __align__(16) unsigned short At[128 * 32];
    __shared__ __align__(16) unsigned short Bt[128 * 32];

    int tid = threadIdx.x;
    int w = tid >> 6, l = tid & 63;
    int wr = w >> 1, wc = w & 1;

    int r1 = tid >> 2, q1 = tid & 3;
    int r2 = r1 + 64;
    const char* aSrc1;
    const char* aSrc2;
    if (G1) {
        int p1 = tm * 128 + r1, p2 = tm * 128 + r2;
        int t1 = tokL[lbase + (p1 < cnt_e ? p1 : 0)];
        int t2 = tokL[lbase + (p2 < cnt_e ? p2 : 0)];
        aSrc1 = (const char*)(A + (size_t)t1 * KD) + ((q1 ^ ((r1 >> 1) & 3)) << 4);
        aSrc2 = (const char*)(A + (size_t)t2 * KD) + ((q1 ^ ((r2 >> 1) & 3)) << 4);
    } else {
        size_t row1 = (size_t)off_e + tm * 128 + r1;
        size_t row2 = row1 + 64;
        aSrc1 = (const char*)(A + row1 * KD) + ((q1 ^ ((r1 >> 1) & 3)) << 4);
        aSrc2 = (const char*)(A + row2 * KD) + ((q1 ^ ((r2 >> 1) & 3)) << 4);
    }
    char* aDst1 = (char*)At + w * 1024;
    char* aDst2 = aDst1 + 4096;

    const float* bSrc[4];
    int bOff[16];
#pragma unroll
    for (int j = 0; j < 4; j++) {
        int fidx = j * 1024 + tid * 4;
        int kk = fidx >> 7, n = fidx & 127;
        bSrc[j] = W + (size_t)eW * KD * ND + (size_t)kk * ND + tn * 128 + n;
#pragma unroll
        for (int i = 0; i < 4; i++) {
            int nn = n + i;
            bOff[j * 4 + i] = nn * 64 + ((((kk >> 3) ^ ((nn >> 1) & 3))) << 4) + ((kk & 7) << 1);
        }
    }

    int aro[4], bro[4];
#pragma unroll
    for (int m = 0; m < 4; m++) {
        int r = wr * 64 + m * 16 + (l & 15);
        aro[m] = r * 64 + (((l >> 4) ^ ((r >> 1) & 3)) << 4);
        int c = wc * 64 + m * 16 + (l & 15);
        bro[m] = c * 64 + (((l >> 4) ^ ((c >> 1) & 3)) << 4);
    }

    f32x4 zf = {0.f, 0.f, 0.f, 0.f};
    f32x4 acc[4][4];
#pragma unroll
    for (int m = 0; m < 4; m++)
#pragma unroll
        for (int n = 0; n < 4; n++) acc[m][n] = zf;

    for (int k0 = 0; k0 < KD; k0 += 32) {
        gld_lds16(aSrc1 + (size_t)k0 * 2, aDst1);
        gld_lds16(aSrc2 + (size_t)k0 * 2, aDst2);
        float4 bv[4];
#pragma unroll
        for (int j = 0; j < 4; j++) bv[j] = *reinterpret_cast<const float4*>(bSrc[j] + (size_t)k0 * ND);
        char* btc = (char*)Bt;
#pragma unroll
        for (int j = 0; j < 4; j++) {
            *(unsigned short*)(btc + bOff[j * 4 + 0]) = f2bf(bv[j].x);
            *(unsigned short*)(btc + bOff[j * 4 + 1]) = f2bf(bv[j].y);
            *(unsigned short*)(btc + bOff[j * 4 + 2]) = f2bf(bv[j].z);
            *(unsigned short*)(btc + bOff[j * 4 + 3]) = f2bf(bv[j].w);
        }
        __syncthreads();
        bf16x8 af[4], bf[4];
#pragma unroll
        for (int m = 0; m < 4; m++) af[m] = *reinterpret_cast<const bf16x8*>((const char*)At + aro[m]);
#pragma unroll
        for (int n = 0; n < 4; n++) bf[n] = *reinterpret_cast<const bf16x8*>((const char*)Bt + bro[n]);
#pragma unroll
        for (int m = 0; m < 4; m++)
#pragma unroll
            for (int n = 0; n < 4; n++)
                acc[m][n] = __builtin_amdgcn_mfma_f32_16x16x32_bf16(af[m], bf[n], acc[m][n], 0, 0, 0);
        __syncthreads();
    }

    if (G1) {
#pragma unroll
        for (int m = 0; m < 4; m++) {
#pragma unroll
            for (int j = 0; j < 4; j++) {
                int rr = wr * 64 + m * 16 + (l >> 4) * 4 + j;
                int p = tm * 128 + rr;
                if (p < cnt_e) {
                    size_t row = (size_t)(off_e + p);
                    unsigned short* hp = H + row * ND + tn * 128 + wc * 64 + (l & 15);
#pragma unroll
                    for (int n = 0; n < 4; n++) {
                        float v = acc[m][n][j];
                        float g = 0.5f * v * (1.f + erff(v * 0.70710678118654752f));
                        hp[n * 16] = f2bf(g);
                    }
                }
            }
        }
    } else {
#pragma unroll
        for (int m = 0; m < 4; m++) {
#pragma unroll
            for (int j = 0; j < 4; j++) {
                int rr = wr * 64 + m * 16 + (l >> 4) * 4 + j;
                int p = tm * 128 + rr;
                if (p < cnt_e) {
                    int t = tokL[lbase + p];
                    float gv = gateL[lbase + p];
                    float* op = O + (size_t)t * ND + tn * 128 + wc * 64 + (l & 15);
#pragma unroll
                    for (int n = 0; n < 4; n++) atomicAdd(op + n * 16, gv * acc[m][n][j]);
                }
            }
        }
    }
}

extern "C" void kernel_launch(void* const* d_in, const int* in_sizes, int n_in,
                              void* d_out, int out_size, void* d_ws, size_t ws_size,
                              hipStream_t stream) {
    const float* x  = (const float*)d_in[0];
    const float* rw = (const float*)d_in[1];
    const float* w1 = (const float*)d_in[2];
    const float* w2 = (const float*)d_in[3];
    float* out = (float*)d_out;
    char* ws = (char*)d_ws;

    int*   cnt  = (int*)ws;                       // 16 counters, 64B apart (1 KB)
    int*   tok  = (int*)(ws + 4096);              // 16*2560 ints
    float* gate = (float*)(ws + 4096 + 16 * CAP * 4);
    unsigned short* xbf = (unsigned short*)(ws + (1 << 20));
    size_t hOff = (1 << 20) + (size_t)N_TOK * HIDD * 2;
    unsigned short* h = (unsigned short*)(ws + hOff);

    size_t w1tSz = (size_t)NE * HIDD * FFND * 2;
    // big: h holds all 16 slots (RMAX rows); mid: h holds 8 slots (8448 rows)
    size_t hBig = (size_t)RMAX * FFND * 2;
    size_t hMid = (size_t)8448 * FFND * 2;
    size_t needBig = hOff + hBig + 2 * w1tSz;
    size_t needMid = hOff + hMid + 2 * w1tSz;

    hipMemsetAsync(cnt, 0, 1024, stream);
    hipMemsetAsync(d_out, 0, (size_t)N_TOK * HIDD * 4, stream);

    hipLaunchKernelGGL(router_kernel, dim3(N_TOK / 32), dim3(256), 0, stream,
                       x, rw, xbf, cnt, tok, gate);

    if (ws_size >= needMid) {
        size_t hSz = (ws_size >= needBig) ? hBig : hMid;
        unsigned short* w1t = (unsigned short*)(ws + hOff + hSz);
        unsigned short* w2t = (unsigned short*)(ws + hOff + hSz + w1tSz);
        hipLaunchKernelGGL((transpose_cvt<HIDD, FFND>), dim3(FFND / 64, HIDD / 64, NE), dim3(256), 0, stream, w1, w1t);
        hipLaunchKernelGGL((transpose_cvt<FFND, HIDD>), dim3(HIDD / 64, FFND / 64, NE), dim3(256), 0, stream, w2, w2t);
        if (ws_size >= needBig) {
            // one merged dispatch per GEMM over all 16 slots
            hipLaunchKernelGGL((ffn_gemm_f<HIDD, FFND, true>), dim3(16 * TMX * (FFND / 128)), dim3(256), 0, stream,
                               xbf, w1t, h, (float*)nullptr, cnt, tok, gate, 0, 0);
            hipLaunchKernelGGL((ffn_gemm_f<FFND, HIDD, false>), dim3(16 * TMX * (HIDD / 128)), dim3(256), 0, stream,
                               h, w2t, (unsigned short*)nullptr, out, cnt, tok, gate, 0, 0);
        } else {
            for (int k = 0; k < 2; k++) {
                hipLaunchKernelGGL((ffn_gemm_f<HIDD, FFND, true>), dim3(8 * TMX * (FFND / 128)), dim3(256), 0, stream,
                                   xbf, w1t, h, (float*)nullptr, cnt, tok, gate, 8 * k, 8 * k);
                hipLaunchKernelGGL((ffn_gemm_f<FFND, HIDD, false>), dim3(8 * TMX * (HIDD / 128)), dim3(256), 0, stream,
                                   h, w2t, (unsigned short*)nullptr, out, cnt, tok, gate, 8 * k, 8 * k);
            }
        }
    } else {
        for (int k = 0; k < 2; k++) {
            hipLaunchKernelGGL((ffn_gemm<HIDD, FFND, true>), dim3(8 * TMX * (FFND / 128)), dim3(256), 0, stream,
                               xbf, w1, h, (float*)nullptr, cnt, tok, gate, 8 * k, 8 * k);
            hipLaunchKernelGGL((ffn_gemm<FFND, HIDD, false>), dim3(8 * TMX * (HIDD / 128)), dim3(256), 0, stream,
                               h, w2, (unsigned short*)nullptr, out, cnt, tok, gate, 8 * k, 8 * k);
        }
    }
}

// Round 4
// 558.849 us; speedup vs baseline: 3.1708x; 1.0596x over previous
//
#include <hip/hip_runtime.h>
#include <hip/hip_bf16.h>
#include <math.h>

#define N_TOK 8192
#define HIDD  1024
#define FFND  4096
#define NE    8
#define CAP   2560
#define TMX   20   // CAP/128
#define RMAX  16512

typedef __attribute__((ext_vector_type(4))) float  f32x4;
typedef __attribute__((ext_vector_type(8))) __bf16 bf16x8;

__device__ __forceinline__ unsigned short f2bf(float f) {
    unsigned u = __float_as_uint(f);
    u = (u + 0x7fffu + ((u >> 16) & 1u)) >> 16;   // RNE
    return (unsigned short)u;
}

__device__ __forceinline__ void gld_lds16(const void* g, void* l) {
    __builtin_amdgcn_global_load_lds(
        (const __attribute__((address_space(1))) unsigned int*)g,
        (__attribute__((address_space(3))) unsigned int*)l, 16, 0, 0);
}

// ---------------- weight fp32 [e][R][C] -> bf16 transposed [e][C][R] ----------------
template <int R, int C>
__global__ __launch_bounds__(256) void transpose_cvt(const float* __restrict__ W,
                                                     unsigned short* __restrict__ Wt) {
    __shared__ unsigned short st[64][72];
    int e  = blockIdx.z;
    int r0 = blockIdx.y * 64, c0 = blockIdx.x * 64;
    int tid = threadIdx.x;
    int rb = tid >> 4, cq = tid & 15;
    const float* src = W + ((size_t)e * R + r0) * C + c0;
#pragma unroll
    for (int i = 0; i < 4; i++) {
        int kr = i * 16 + rb;
        float4 v = *reinterpret_cast<const float4*>(src + (size_t)kr * C + cq * 4);
        st[cq * 4 + 0][kr] = f2bf(v.x);
        st[cq * 4 + 1][kr] = f2bf(v.y);
        st[cq * 4 + 2][kr] = f2bf(v.z);
        st[cq * 4 + 3][kr] = f2bf(v.w);
    }
    __syncthreads();
    unsigned short* dst = Wt + ((size_t)e * C + c0) * R + r0;
#pragma unroll
    for (int i = 0; i < 4; i++) {
        int cr = i * 16 + rb;
        uint2 v = *reinterpret_cast<const uint2*>(&st[cr][cq * 4]);
        *reinterpret_cast<uint2*>(dst + (size_t)cr * R + cq * 4) = v;
    }
}

// ---------------- fused router + x->bf16: 32 tokens/block, block-aggregated counts ----
__global__ __launch_bounds__(256) void router_kernel(const float* __restrict__ x,
                                                     const float* __restrict__ rw,
                                                     unsigned short* __restrict__ xbf,
                                                     int* __restrict__ cnt,
                                                     int* __restrict__ tok,
                                                     float* __restrict__ gate) {
    __shared__ float4 rwl[2048];          // 32 KB: rw as float4
    __shared__ int   e0s[32], e1s[32];
    __shared__ float g0s[32], g1s[32];
    __shared__ int   baseS[16];

    int tid = threadIdx.x, lane = tid & 63, w = tid >> 6;
    for (int i = tid; i < 2048; i += 256) rwl[i] = reinterpret_cast<const float4*>(rw)[i];
    __syncthreads();

    int tbase = blockIdx.x * 32 + w * 8;
    for (int i = 0; i < 8; i++) {
        int t = tbase + i;
        const float4* xr = reinterpret_cast<const float4*>(x) + (size_t)t * 256;
        float4 xv[4];
#pragma unroll
        for (int c = 0; c < 4; c++) xv[c] = xr[c * 64 + lane];
        uint2* xb = reinterpret_cast<uint2*>(xbf) + (size_t)t * 256;
#pragma unroll
        for (int c = 0; c < 4; c++) {
            uint2 p;
            p.x = (unsigned)f2bf(xv[c].x) | ((unsigned)f2bf(xv[c].y) << 16);
            p.y = (unsigned)f2bf(xv[c].z) | ((unsigned)f2bf(xv[c].w) << 16);
            xb[c * 64 + lane] = p;
        }
        float dot[NE];
#pragma unroll
        for (int e = 0; e < NE; e++) {
            float s = 0.f;
#pragma unroll
            for (int c = 0; c < 4; c++) {
                float4 a = rwl[e * 256 + c * 64 + lane];
                s += xv[c].x * a.x + xv[c].y * a.y + xv[c].z * a.z + xv[c].w * a.w;
            }
            dot[e] = s;
        }
#pragma unroll
        for (int e = 0; e < NE; e++) {
            float v = dot[e];
#pragma unroll
            for (int o = 32; o > 0; o >>= 1) v += __shfl_xor(v, o, 64);
            dot[e] = v;
        }
        if (lane == 0) {
            int e0 = 0; float l0 = dot[0];
#pragma unroll
            for (int e = 1; e < NE; e++) if (dot[e] > l0) { l0 = dot[e]; e0 = e; }
            int e1 = -1; float l1 = -3.4e38f;
#pragma unroll
            for (int e = 0; e < NE; e++) if (e != e0 && dot[e] > l1) { l1 = dot[e]; e1 = e; }
            float g0 = 1.f / (1.f + expf(l1 - l0));
            int j = w * 8 + i;
            e0s[j] = e0; e1s[j] = e1; g0s[j] = g0; g1s[j] = 1.f - g0;
        }
    }
    __syncthreads();

    int e0 = 255, e1 = 255, rank0 = 0, rank1 = 0, slotcnt = 0;
    float g0 = 0.f, g1 = 0.f;
    if (w == 0) {
        if (lane < 32) { e0 = e0s[lane]; e1 = e1s[lane]; g0 = g0s[lane]; g1 = g1s[lane]; }
        unsigned long long lt = (1ull << lane) - 1ull;
#pragma unroll
        for (int ee = 0; ee < NE; ee++) {
            unsigned long long m0 = __ballot(e0 == ee);
            unsigned long long m1 = __ballot(e1 == ee);
            if (e0 == ee) rank0 = (int)__popcll(m0 & lt);
            if (e1 == ee) rank1 = (int)__popcll(m1 & lt);
            if (lane == ee)      slotcnt = (int)__popcll(m0);
            if (lane == NE + ee) slotcnt = (int)__popcll(m1);
        }
        if (lane < 16) baseS[lane] = atomicAdd(&cnt[lane * 16], slotcnt);
    }
    __syncthreads();
    if (w == 0 && lane < 32) {
        int t = blockIdx.x * 32 + lane;
        int p0 = baseS[e0] + rank0;
        if (p0 < CAP) { tok[e0 * CAP + p0] = t; gate[e0 * CAP + p0] = g0; }
        int p1 = baseS[NE + e1] + rank1;
        if (p1 < CAP) { tok[(NE + e1) * CAP + p1] = t; gate[(NE + e1) * CAP + p1] = g1; }
    }
}

// ======== FAST GEMM: XCD-homed (expert = bid&7), chunked tn, slot-interleaved, tm-major ========
// work decode: xcd handles slots {e, e+8} (same expert weights). Within chunk c of CH tn-tiles:
// slot0's (tm x CH) blocks then slot1's -> B-panels of the chunk stay L2-hot across both slots.
template <int KD, int ND, bool G1, int CH>
__global__ __launch_bounds__(256) void ffn_gemm_f(const unsigned short* __restrict__ A,
                                                  const unsigned short* __restrict__ Bw, // [e][n][k]
                                                  unsigned short* __restrict__ H,
                                                  float* __restrict__ O,
                                                  const int* __restrict__ cntAll,
                                                  const int* __restrict__ tokL,
                                                  const float* __restrict__ gateL) {
    constexpr int TN = ND / 128;
    int e = blockIdx.x & 7;
    int i = blockIdx.x >> 3;
    int cnt0 = min(cntAll[e * 16], CAP);
    int cnt1 = min(cntAll[(e + 8) * 16], CAP);
    int tmx0 = (cnt0 + 127) >> 7;
    int tmx1 = (cnt1 + 127) >> 7;
    int tmsum = tmx0 + tmx1;
    if (tmsum == 0) return;
    int per_chunk = tmsum * CH;
    int c = i / per_chunk;
    if (c >= TN / CH) return;
    int r = i - c * per_chunk;
    int s, tm, cnt_e;
    int t0 = tmx0 * CH;
    if (r < t0) { s = e;     tm = r / CH; r -= tm * CH; cnt_e = cnt0; }
    else { r -= t0; s = e + 8; tm = r / CH; r -= tm * CH; cnt_e = cnt1; }
    int tn = c * CH + r;

    int off_e = 0;
#pragma unroll
    for (int t = 0; t < 16; t++) off_e += (t < s) ? min(cntAll[t * 16], CAP) : 0;
    const int lbase = s * CAP;

    __shared__ __align__(16) unsigned short At[128 * 32];
    __shared__ __align__(16) unsigned short Bt[128 * 32];

    int tid = threadIdx.x;
    int w = tid >> 6, l = tid & 63;
    int wr = w >> 1, wc = w & 1;

    int r1 = tid >> 2, q1 = tid & 3;
    int r2 = r1 + 64;

    const char* aSrc1;
    const char* aSrc2;
    if (G1) {
        int p1 = tm * 128 + r1, p2 = tm * 128 + r2;
        int t1 = tokL[lbase + (p1 < cnt_e ? p1 : 0)];
        int t2 = tokL[lbase + (p2 < cnt_e ? p2 : 0)];
        aSrc1 = (const char*)(A + (size_t)t1 * KD) + ((q1 ^ ((r1 >> 1) & 3)) << 4);
        aSrc2 = (const char*)(A + (size_t)t2 * KD) + ((q1 ^ ((r2 >> 1) & 3)) << 4);
    } else {
        size_t row1 = (size_t)off_e + tm * 128 + r1;
        size_t row2 = row1 + 64;
        aSrc1 = (const char*)(A + row1 * KD) + ((q1 ^ ((r1 >> 1) & 3)) << 4);
        aSrc2 = (const char*)(A + row2 * KD) + ((q1 ^ ((r2 >> 1) & 3)) << 4);
    }
    const char* bSrc1 = (const char*)(Bw + ((size_t)e * ND + tn * 128 + r1) * KD) + ((q1 ^ ((r1 >> 1) & 3)) << 4);
    const char* bSrc2 = (const char*)(Bw + ((size_t)e * ND + tn * 128 + r2) * KD) + ((q1 ^ ((r2 >> 1) & 3)) << 4);

    char* aDst1 = (char*)At + w * 1024;
    char* aDst2 = aDst1 + 4096;
    char* bDst1 = (char*)Bt + w * 1024;
    char* bDst2 = bDst1 + 4096;

    int aro[4], bro[4];
#pragma unroll
    for (int m = 0; m < 4; m++) {
        int rr = wr * 64 + m * 16 + (l & 15);
        aro[m] = rr * 64 + (((l >> 4) ^ ((rr >> 1) & 3)) << 4);
        int cc = wc * 64 + m * 16 + (l & 15);
        bro[m] = cc * 64 + (((l >> 4) ^ ((cc >> 1) & 3)) << 4);
    }

    f32x4 zf = {0.f, 0.f, 0.f, 0.f};
    f32x4 acc[4][4];
#pragma unroll
    for (int m = 0; m < 4; m++)
#pragma unroll
        for (int n = 0; n < 4; n++) acc[m][n] = zf;

    for (int k0 = 0; k0 < KD; k0 += 32) {
        size_t kb = (size_t)k0 * 2;
        gld_lds16(aSrc1 + kb, aDst1);
        gld_lds16(aSrc2 + kb, aDst2);
        gld_lds16(bSrc1 + kb, bDst1);
        gld_lds16(bSrc2 + kb, bDst2);
        __syncthreads();
        bf16x8 af[4], bf[4];
#pragma unroll
        for (int m = 0; m < 4; m++) af[m] = *reinterpret_cast<const bf16x8*>((const char*)At + aro[m]);
#pragma unroll
        for (int n = 0; n < 4; n++) bf[n] = *reinterpret_cast<const bf16x8*>((const char*)Bt + bro[n]);
#pragma unroll
        for (int m = 0; m < 4; m++)
#pragma unroll
            for (int n = 0; n < 4; n++)
                acc[m][n] = __builtin_amdgcn_mfma_f32_16x16x32_bf16(af[m], bf[n], acc[m][n], 0, 0, 0);
        __syncthreads();
    }

    if (G1) {
#pragma unroll
        for (int m = 0; m < 4; m++) {
#pragma unroll
            for (int j = 0; j < 4; j++) {
                int rr = wr * 64 + m * 16 + (l >> 4) * 4 + j;
                int p = tm * 128 + rr;
                if (p < cnt_e) {
                    size_t row = (size_t)(off_e + p);
                    unsigned short* hp = H + row * ND + tn * 128 + wc * 64 + (l & 15);
#pragma unroll
                    for (int n = 0; n < 4; n++) {
                        float v = acc[m][n][j];
                        float g = 0.5f * v * (1.f + erff(v * 0.70710678118654752f));
                        hp[n * 16] = f2bf(g);
                    }
                }
            }
        }
    } else {
#pragma unroll
        for (int m = 0; m < 4; m++) {
#pragma unroll
            for (int j = 0; j < 4; j++) {
                int rr = wr * 64 + m * 16 + (l >> 4) * 4 + j;
                int p = tm * 128 + rr;
                if (p < cnt_e) {
                    int t = tokL[lbase + p];
                    float gv = gateL[lbase + p];
                    float* op = O + (size_t)t * ND + tn * 128 + wc * 64 + (l & 15);
#pragma unroll
                    for (int n = 0; n < 4; n++) atomicAdd(op + n * 16, gv * acc[m][n][j]);
                }
            }
        }
    }
}

// ======== FALLBACK path (fp32 weights on the fly; used only if ws is small) ========
template <int KD, int ND, bool G1>
__global__ __launch_bounds__(256) void ffn_gemm(const unsigned short* __restrict__ A,
                                                const float* __restrict__ W,
                                                unsigned short* __restrict__ H,
                                                float* __restrict__ O,
                                                const int* __restrict__ cntAll,
                                                const int* __restrict__ tokL,
                                                const float* __restrict__ gateL,
                                                int slot0, int pbase) {
    constexpr int TN = ND / 128;
    int bid = blockIdx.x;
    int tn  = bid % TN;
    int tme = bid / TN;
    int tm  = tme % TMX;
    int s   = slot0 + tme / TMX;
    int eW  = s & 7;
    int cnt_e = min(cntAll[s * 16], CAP);
    if (tm * 128 >= cnt_e) return;
    int off_e = 0;
#pragma unroll
    for (int i = 0; i < 16; i++) {
        int c = min(cntAll[i * 16], CAP);
        off_e += (i >= pbase && i < s) ? c : 0;
    }
    const int lbase = s * CAP;

    __shared__ __align__(16) unsigned short At[128 * 32];
    __shared__ __align__(16) unsigned short Bt[128 * 32];

    int tid = threadIdx.x;
    int w = tid >> 6, l = tid & 63;
    int wr = w >> 1, wc = w & 1;

    int r1 = tid >> 2, q1 = tid & 3;
    int r2 = r1 + 64;
    const char* aSrc1;
    const char* aSrc2;
    if (G1) {
        int p1 = tm * 128 + r1, p2 = tm * 128 + r2;
        int t1 = tokL[lbase + (p1 < cnt_e ? p1 : 0)];
        int t2 = tokL[lbase + (p2 < cnt_e ? p2 : 0)];
        aSrc1 = (const char*)(A + (size_t)t1 * KD) + ((q1 ^ ((r1 >> 1) & 3)) << 4);
        aSrc2 = (const char*)(A + (size_t)t2 * KD) + ((q1 ^ ((r2 >> 1) & 3)) << 4);
    } else {
        size_t row1 = (size_t)off_e + tm * 128 + r1;
        size_t row2 = row1 + 64;
        aSrc1 = (const char*)(A + row1 * KD) + ((q1 ^ ((r1 >> 1) & 3)) << 4);
        aSrc2 = (const char*)(A + row2 * KD) + ((q1 ^ ((r2 >> 1) & 3)) << 4);
    }
    char* aDst1 = (char*)At + w * 1024;
    char* aDst2 = aDst1 + 4096;

    const float* bSrc[4];
    int bOff[16];
#pragma unroll
    for (int j = 0; j < 4; j++) {
        int fidx = j * 1024 + tid * 4;
        int kk = fidx >> 7, n = fidx & 127;
        bSrc[j] = W + (size_t)eW * KD * ND + (size_t)kk * ND + tn * 128 + n;
#pragma unroll
        for (int i = 0; i < 4; i++) {
            int nn = n + i;
            bOff[j * 4 + i] = nn * 64 + ((((kk >> 3) ^ ((nn >> 1) & 3))) << 4) + ((kk & 7) << 1);
        }
    }

    int aro[4], bro[4];
#pragma unroll
    for (int m = 0; m < 4; m++) {
        int rr = wr * 64 + m * 16 + (l & 15);
        aro[m] = rr * 64 + (((l >> 4) ^ ((rr >> 1) & 3)) << 4);
        int cc = wc * 64 + m * 16 + (l & 15);
        bro[m] = cc * 64 + (((l >> 4) ^ ((cc >> 1) & 3)) << 4);
    }

    f32x4 zf = {0.f, 0.f, 0.f, 0.f};
    f32x4 acc[4][4];
#pragma unroll
    for (int m = 0; m < 4; m++)
#pragma unroll
        for (int n = 0; n < 4; n++) acc[m][n] = zf;

    for (int k0 = 0; k0 < KD; k0 += 32) {
        gld_lds16(aSrc1 + (size_t)k0 * 2, aDst1);
        gld_lds16(aSrc2 + (size_t)k0 * 2, aDst2);
        float4 bv[4];
#pragma unroll
        for (int j = 0; j < 4; j++) bv[j] = *reinterpret_cast<const float4*>(bSrc[j] + (size_t)k0 * ND);
        char* btc = (char*)Bt;
#pragma unroll
        for (int j = 0; j < 4; j++) {
            *(unsigned short*)(btc + bOff[j * 4 + 0]) = f2bf(bv[j].x);
            *(unsigned short*)(btc + bOff[j * 4 + 1]) = f2bf(bv[j].y);
            *(unsigned short*)(btc + bOff[j * 4 + 2]) = f2bf(bv[j].z);
            *(unsigned short*)(btc + bOff[j * 4 + 3]) = f2bf(bv[j].w);
        }
        __syncthreads();
        bf16x8 af[4], bf[4];
#pragma unroll
        for (int m = 0; m < 4; m++) af[m] = *reinterpret_cast<const bf16x8*>((const char*)At + aro[m]);
#pragma unroll
        for (int n = 0; n < 4; n++) bf[n] = *reinterpret_cast<const bf16x8*>((const char*)Bt + bro[n]);
#pragma unroll
        for (int m = 0; m < 4; m++)
#pragma unroll
            for (int n = 0; n < 4; n++)
                acc[m][n] = __builtin_amdgcn_mfma_f32_16x16x32_bf16(af[m], bf[n], acc[m][n], 0, 0, 0);
        __syncthreads();
    }

    if (G1) {
#pragma unroll
        for (int m = 0; m < 4; m++) {
#pragma unroll
            for (int j = 0; j < 4; j++) {
                int rr = wr * 64 + m * 16 + (l >> 4) * 4 + j;
                int p = tm * 128 + rr;
                if (p < cnt_e) {
                    size_t row = (size_t)(off_e + p);
                    unsigned short* hp = H + row * ND + tn * 128 + wc * 64 + (l & 15);
#pragma unroll
                    for (int n = 0; n < 4; n++) {
                        float v = acc[m][n][j];
                        float g = 0.5f * v * (1.f + erff(v * 0.70710678118654752f));
                        hp[n * 16] = f2bf(g);
                    }
                }
            }
        }
    } else {
#pragma unroll
        for (int m = 0; m < 4; m++) {
#pragma unroll
            for (int j = 0; j < 4; j++) {
                int rr = wr * 64 + m * 16 + (l >> 4) * 4 + j;
                int p = tm * 128 + rr;
                if (p < cnt_e) {
                    int t = tokL[lbase + p];
                    float gv = gateL[lbase + p];
                    float* op = O + (size_t)t * ND + tn * 128 + wc * 64 + (l & 15);
#pragma unroll
                    for (int n = 0; n < 4; n++) atomicAdd(op + n * 16, gv * acc[m][n][j]);
                }
            }
        }
    }
}

extern "C" void kernel_launch(void* const* d_in, const int* in_sizes, int n_in,
                              void* d_out, int out_size, void* d_ws, size_t ws_size,
                              hipStream_t stream) {
    const float* x  = (const float*)d_in[0];
    const float* rw = (const float*)d_in[1];
    const float* w1 = (const float*)d_in[2];
    const float* w2 = (const float*)d_in[3];
    float* out = (float*)d_out;
    char* ws = (char*)d_ws;

    int*   cnt  = (int*)ws;                       // 16 counters, 64B apart (1 KB)
    int*   tok  = (int*)(ws + 4096);              // 16*2560 ints
    float* gate = (float*)(ws + 4096 + 16 * CAP * 4);
    unsigned short* xbf = (unsigned short*)(ws + (1 << 20));
    size_t hOff = (1 << 20) + (size_t)N_TOK * HIDD * 2;
    unsigned short* h = (unsigned short*)(ws + hOff);

    size_t w1tSz = (size_t)NE * HIDD * FFND * 2;
    size_t hBig = (size_t)RMAX * FFND * 2;
    size_t needBig = hOff + hBig + 2 * w1tSz;

    hipMemsetAsync(cnt, 0, 1024, stream);
    hipMemsetAsync(d_out, 0, (size_t)N_TOK * HIDD * 4, stream);

    hipLaunchKernelGGL(router_kernel, dim3(N_TOK / 32), dim3(256), 0, stream,
                       x, rw, xbf, cnt, tok, gate);

    if (ws_size >= needBig) {
        unsigned short* w1t = (unsigned short*)(ws + hOff + hBig);
        unsigned short* w2t = (unsigned short*)(ws + hOff + hBig + w1tSz);
        hipLaunchKernelGGL((transpose_cvt<HIDD, FFND>), dim3(FFND / 64, HIDD / 64, NE), dim3(256), 0, stream, w1, w1t);
        hipLaunchKernelGGL((transpose_cvt<FFND, HIDD>), dim3(HIDD / 64, FFND / 64, NE), dim3(256), 0, stream, w2, w2t);
        // homed grids: 8 XCDs x (2 slots x TMX x TN) upper bound
        hipLaunchKernelGGL((ffn_gemm_f<HIDD, FFND, true, 8>), dim3(8 * 2 * TMX * (FFND / 128)), dim3(256), 0, stream,
                           xbf, w1t, h, (float*)nullptr, cnt, tok, gate);
        hipLaunchKernelGGL((ffn_gemm_f<FFND, HIDD, false, 4>), dim3(8 * 2 * TMX * (HIDD / 128)), dim3(256), 0, stream,
                           h, w2t, (unsigned short*)nullptr, out, cnt, tok, gate);
    } else {
        for (int k = 0; k < 2; k++) {
            hipLaunchKernelGGL((ffn_gemm<HIDD, FFND, true>), dim3(8 * TMX * (FFND / 128)), dim3(256), 0, stream,
                               xbf, w1, h, (float*)nullptr, cnt, tok, gate, 8 * k, 8 * k);
            hipLaunchKernelGGL((ffn_gemm<FFND, HIDD, false>), dim3(8 * TMX * (HIDD / 128)), dim3(256), 0, stream,
                               h, w2, (unsigned short*)nullptr, out, cnt, tok, gate, 8 * k, 8 * k);
        }
    }
}